// Round 6
// baseline (138.568 us; speedup 1.0000x reference)
//
#include <hip/hip_runtime.h>

// ---------------------------------------------------------------------------
// DagLinkExtractor: B=8, N=1024, HID=1024, NH=4, HD=256
// out[b,i,j] = log Σ_h exp(s_h)·ec[b,h,i]   (alive), else -1e9
//   s = (Q_h . K_h)/16  (1/16 folded into stored Q)
//   ec[b,h,i] = exp(log_gate) / Z,  Z = Σ_{valid j>i} exp(s)
// Score passes read K/Q fragments DIRECTLY from L2 (no LDS staging):
// swapped MFMA  D = mfma(K_frag, Q_frag)  ->  D col = i (lr), row = j (lg4*4+r)
// ---------------------------------------------------------------------------

typedef __attribute__((ext_vector_type(8))) short bf16x8;
typedef __attribute__((ext_vector_type(4))) float f32x4;

#define LB __launch_bounds__(256)

__device__ __forceinline__ short f2bf(float f) {
    unsigned u = __float_as_uint(f);
    u += 0x7fffu + ((u >> 16) & 1u);   // RNE
    return (short)(u >> 16);
}

__device__ __forceinline__ void gld16(const void* g, void* l) {
    __builtin_amdgcn_global_load_lds(
        (const __attribute__((address_space(1))) unsigned int*)g,
        (__attribute__((address_space(3))) unsigned int*)l, 16, 0, 0);
}

// ---- 1. fused: Xb = bf16(features), lgA = log_softmax(features@Wg+bg) -------
__global__ LB void k_prep(const float* __restrict__ feat, const float* __restrict__ Wg,
                          const float* __restrict__ bg, short* __restrict__ Xb,
                          float* __restrict__ lgA) {
    int row = blockIdx.x * 4 + (threadIdx.x >> 6);
    int lane = threadIdx.x & 63;
    const float* f = feat + (size_t)row * 1024;
    float g0 = 0.f, g1 = 0.f, g2 = 0.f, g3 = 0.f;
#pragma unroll
    for (int tt = 0; tt < 4; ++tt) {
        int k = tt * 256 + lane * 4;
        float4 x = *(const float4*)&f[k];
        float4 w0 = *(const float4*)&Wg[(k + 0) * 4];
        float4 w1 = *(const float4*)&Wg[(k + 1) * 4];
        float4 w2 = *(const float4*)&Wg[(k + 2) * 4];
        float4 w3 = *(const float4*)&Wg[(k + 3) * 4];
        g0 += x.x * w0.x + x.y * w1.x + x.z * w2.x + x.w * w3.x;
        g1 += x.x * w0.y + x.y * w1.y + x.z * w2.y + x.w * w3.y;
        g2 += x.x * w0.z + x.y * w1.z + x.z * w2.z + x.w * w3.z;
        g3 += x.x * w0.w + x.y * w1.w + x.z * w2.w + x.w * w3.w;
        __attribute__((ext_vector_type(4))) short xv;
        xv[0] = f2bf(x.x); xv[1] = f2bf(x.y); xv[2] = f2bf(x.z); xv[3] = f2bf(x.w);
        *(__attribute__((ext_vector_type(4))) short*)&Xb[(size_t)row * 1024 + k] = xv;
    }
#pragma unroll
    for (int off = 32; off; off >>= 1) {
        g0 += __shfl_xor(g0, off); g1 += __shfl_xor(g1, off);
        g2 += __shfl_xor(g2, off); g3 += __shfl_xor(g3, off);
    }
    g0 += bg[0]; g1 += bg[1]; g2 += bg[2]; g3 += bg[3];
    float m = fmaxf(fmaxf(g0, g1), fmaxf(g2, g3));
    float s = __expf(g0 - m) + __expf(g1 - m) + __expf(g2 - m) + __expf(g3 - m);
    float ls = m + __logf(s);
    if (lane == 0) {
        float4 o = {g0 - ls, g1 - ls, g2 - ls, g3 - ls};
        *(float4*)&lgA[row * 4] = o;
    }
}

// ---- 2. Wt[n][k] = W[k][n] (bf16), n<1024 -> Wq, else Wk --------------------
__global__ LB void k_cvt_w(const float* __restrict__ Wq, const float* __restrict__ Wk,
                           short* __restrict__ Wt) {
    __shared__ float tile[32][33];
    int n0 = blockIdx.x * 32, k0 = blockIdx.y * 32;
    const float* W = (n0 < 1024) ? Wq : Wk;
    int nb = n0 & 1023;
    int tx = threadIdx.x, ty = threadIdx.y;
#pragma unroll
    for (int jj = 0; jj < 4; ++jj) {
        int k = ty + jj * 8;
        tile[k][tx] = W[(size_t)(k0 + k) * 1024 + nb + tx];
    }
    __syncthreads();
#pragma unroll
    for (int jj = 0; jj < 4; ++jj) {
        int n = ty + jj * 8;
        Wt[(size_t)(n0 + n) * 1024 + k0 + tx] = f2bf(tile[tx][n]);
    }
}

// ---- 3. GEMM 256x256 tile, BK=64, 4-quadrant-phase, counted vmcnt -----------
__global__ __launch_bounds__(512, 2) void k_gemm(const short* __restrict__ Xb,
                                                 const short* __restrict__ Wt,
                                                 const float* __restrict__ bq,
                                                 const float* __restrict__ bk,
                                                 short* __restrict__ Qb,
                                                 short* __restrict__ Kb) {
    __shared__ short As[2][16384];                 // 2 x 32 KB: [256][64] bf16
    __shared__ short Bs[2][16384];
    const int t = threadIdx.x;
    const int lane = t & 63, wid = t >> 6;
    const int wr = wid >> 2, wc = wid & 3;         // 2 x 4 waves
    const int lr = lane & 15, lg4 = lane >> 4;
    const int wgid = (blockIdx.x & 7) * 32 + (blockIdx.x >> 3);
    const int mt = wgid >> 3, nt = wgid & 7;
    const int m0t = mt * 256, n0t = nt * 256;

    f32x4 acc[8][4] = {};

#define STAGE_A(q, k1, dst)                                                     \
    { int s_ = (q) * 512 + t; int tr_ = s_ >> 3, sl_ = s_ & 7;                  \
      gld16(&Xb[(size_t)(m0t + tr_) * 1024 + (k1) + ((sl_ ^ (tr_ & 7)) * 8)],   \
            &(dst)[s_ * 8]); }
#define STAGE_B(q, k1, dst)                                                     \
    { int s_ = (q) * 512 + t; int tr_ = s_ >> 3, sl_ = s_ & 7;                  \
      gld16(&Wt[(size_t)(n0t + tr_) * 1024 + (k1) + ((sl_ ^ (tr_ & 7)) * 8)],   \
            &(dst)[s_ * 8]); }

    {
        short* Ad = As[0]; short* Bd = Bs[0];
        STAGE_A(0, 0, Ad); STAGE_A(1, 0, Ad); STAGE_A(2, 0, Ad); STAGE_A(3, 0, Ad);
        STAGE_B(0, 0, Bd); STAGE_B(1, 0, Bd); STAGE_B(2, 0, Bd); STAGE_B(3, 0, Bd);
    }
    asm volatile("s_waitcnt vmcnt(0)" ::: "memory");
    __builtin_amdgcn_sched_barrier(0);
    __builtin_amdgcn_s_barrier();

    for (int kt = 0; kt < 16; ++kt) {
        const int cur = kt & 1;
        const short* Ac = As[cur];
        const short* Bc = Bs[cur];
        short* Ad = As[cur ^ 1];
        short* Bd = Bs[cur ^ 1];
        const int k1 = (kt + 1) * 64;
#pragma unroll
        for (int p = 0; p < 4; ++p) {
            const int mh = p >> 1, nh = p & 1;
            bf16x8 aF[4][2], bF[2][2];
#pragma unroll
            for (int m = 0; m < 4; ++m)
#pragma unroll
                for (int ks = 0; ks < 2; ++ks) {
                    int row = wr * 128 + mh * 64 + m * 16 + lr;
                    aF[m][ks] = *(const bf16x8*)
                        &Ac[row * 64 + (((ks * 4 + lg4) ^ (lr & 7)) * 8)];
                }
#pragma unroll
            for (int n = 0; n < 2; ++n)
#pragma unroll
                for (int ks = 0; ks < 2; ++ks) {
                    int row = wc * 64 + (nh * 2 + n) * 16 + lr;
                    bF[n][ks] = *(const bf16x8*)
                        &Bc[row * 64 + (((ks * 4 + lg4) ^ (lr & 7)) * 8)];
                }
            if (kt < 15) {
                if (p == 0)      { STAGE_A(0, k1, Ad); STAGE_A(2, k1, Ad); }
                else if (p == 1) { STAGE_B(0, k1, Bd); STAGE_B(1, k1, Bd); }
                else if (p == 2) { STAGE_B(2, k1, Bd); STAGE_B(3, k1, Bd); }
                else             { STAGE_A(1, k1, Ad); STAGE_A(3, k1, Ad); }
            }
            if (p == 1) {
                if (kt < 15) asm volatile("s_waitcnt vmcnt(4)" ::: "memory");
                else         asm volatile("s_waitcnt vmcnt(0)" ::: "memory");
            } else if (p == 3 && kt < 15) {
                asm volatile("s_waitcnt vmcnt(2)" ::: "memory");
            }
            __builtin_amdgcn_sched_barrier(0);
            __builtin_amdgcn_s_barrier();
            asm volatile("s_waitcnt lgkmcnt(0)" ::: "memory");
            __builtin_amdgcn_sched_barrier(0);
            __builtin_amdgcn_s_setprio(1);
#pragma unroll
            for (int ks = 0; ks < 2; ++ks)
#pragma unroll
                for (int m = 0; m < 4; ++m)
#pragma unroll
                    for (int n = 0; n < 2; ++n)
                        acc[mh * 4 + m][nh * 2 + n] =
                            __builtin_amdgcn_mfma_f32_16x16x32_bf16(
                                aF[m][ks], bF[n][ks], acc[mh * 4 + m][nh * 2 + n],
                                0, 0, 0);
            __builtin_amdgcn_s_setprio(0);
        }
    }
#undef STAGE_A
#undef STAGE_B

#pragma unroll
    for (int mf = 0; mf < 8; ++mf) {
#pragma unroll
        for (int nf = 0; nf < 4; ++nf) {
            int col = n0t + wc * 64 + nf * 16 + lr;
            float bias = (col < 1024) ? bq[col] : bk[col - 1024];
            float scale = (col < 1024) ? 0.0625f : 1.0f;
            short* dst = (col < 1024) ? Qb : Kb;
            int h = (col >> 8) & 3, d = col & 255;
#pragma unroll
            for (int r = 0; r < 4; ++r) {
                int rowg = m0t + wr * 128 + mf * 16 + lg4 * 4 + r;
                int b_ = rowg >> 10, i_ = rowg & 1023;
                float v = (acc[mf][nf][r] + bias) * scale;
                dst[((size_t)(b_ * 4 + h) * 1024 + i_) * 256 + d] = f2bf(v);
            }
        }
    }
}

// ---- 4. k_z: Z partials, LDS-free, barrier-free -----------------------------
// wave = (bh, 64-i strip, j-quarter); Q 4x8 frags pinned; K direct from L2.
__global__ __launch_bounds__(256, 2) void k_z(const short* __restrict__ Qb,
                                              const short* __restrict__ Kb,
                                              const int* __restrict__ vm,
                                              float* __restrict__ Zp) {
    const int t = threadIdx.x, lane = t & 63, h = t >> 6;   // wave id = head
    const int bid = blockIdx.x;
    const int b = bid & 7, r = bid >> 3;                    // XCD owns one b
    const int strip = r >> 2, jq = r & 3;
    const int i0blk = strip * 64;
    const int jlo = jq * 256, jhi = jlo + 256;
    const int lr = lane & 15, lg4 = lane >> 4;
    const int bh = b * 4 + h;

    bf16x8 qF[4][8];
#pragma unroll
    for (int set = 0; set < 4; ++set) {
        const short* qrow = &Qb[((size_t)bh * 1024 + i0blk + set * 16 + lr) * 256];
#pragma unroll
        for (int kk = 0; kk < 8; ++kk)
            qF[set][kk] = *(const bf16x8*)&qrow[kk * 32 + lg4 * 8];
    }
#pragma unroll
    for (int set = 0; set < 4; ++set)
#pragma unroll
        for (int kk = 0; kk < 8; ++kk) asm volatile("" : "+v"(qF[set][kk]));

    float Zl[4] = {0.f, 0.f, 0.f, 0.f};
    const int jstart = (jlo > i0blk) ? jlo : i0blk;
    for (int js = jstart; js < jhi; js += 16) {
        bf16x8 kF[8];
        const short* krow = &Kb[((size_t)bh * 1024 + js + lr) * 256];
#pragma unroll
        for (int kk = 0; kk < 8; ++kk)
            kF[kk] = *(const bf16x8*)&krow[kk * 32 + lg4 * 8];
        f32x4 s[4] = {};
#pragma unroll
        for (int kk = 0; kk < 8; ++kk)
#pragma unroll
            for (int set = 0; set < 4; ++set)
                s[set] = __builtin_amdgcn_mfma_f32_16x16x32_bf16(
                    kF[kk], qF[set][kk], s[set], 0, 0, 0);
        int4 v4 = *(const int4*)&vm[(b << 10) + js + lg4 * 4];
        const int jb = js + lg4 * 4;
#pragma unroll
        for (int set = 0; set < 4; ++set) {
            const int iL = i0blk + set * 16 + lr;
            Zl[set] += (v4.x && (jb + 0 > iL)) ? __expf(s[set][0]) : 0.f;
            Zl[set] += (v4.y && (jb + 1 > iL)) ? __expf(s[set][1]) : 0.f;
            Zl[set] += (v4.z && (jb + 2 > iL)) ? __expf(s[set][2]) : 0.f;
            Zl[set] += (v4.w && (jb + 3 > iL)) ? __expf(s[set][3]) : 0.f;
        }
    }
#pragma unroll
    for (int set = 0; set < 4; ++set) {
        Zl[set] += __shfl_xor(Zl[set], 16);
        Zl[set] += __shfl_xor(Zl[set], 32);
    }
    if (lane < 16) {
#pragma unroll
        for (int set = 0; set < 4; ++set)
            Zp[jq * 32768 + bh * 1024 + i0blk + set * 16 + lane] = Zl[set];
    }
}

// ---- 5. ecT[bh][i] = exp(lg) / Z  (Z==0 -> 0, row dead) ---------------------
__global__ LB void k_c(const float* __restrict__ lgA, const float* __restrict__ Zp,
                       float* __restrict__ ecT) {
    int idx = blockIdx.x * 256 + threadIdx.x;      // 32768 = bh*1024 + i
    int bh = idx >> 10, i = idx & 1023;
    int b = bh >> 2, h = bh & 3;
    float Zv = Zp[idx] + Zp[32768 + idx] + Zp[65536 + idx] + Zp[98304 + idx];
    float lg = lgA[((b << 10) + i) * 4 + h];
    ecT[idx] = (Zv > 0.f) ? __expf(lg) / Zv : 0.f;
}

// ---- 6. out pass: block = (b, 64-i strip, j-quarter), 4 waves = 4 heads -----
// Per 16-j subtile: each wave mfma(K,Q) its head, writes exp(s)*ec to dbuf
// LDS plane (pad 17), ONE raw barrier, block combines log(sum) -> float4 out.
__global__ __launch_bounds__(256, 2) void k_out2(const short* __restrict__ Qb,
                                                 const short* __restrict__ Kb,
                                                 const int* __restrict__ vm,
                                                 const float* __restrict__ ecT,
                                                 float* __restrict__ out) {
    __shared__ float Pb[2][4][64][17];             // 34.8 KB
    const int t = threadIdx.x, lane = t & 63, h = t >> 6;
    const int bid = blockIdx.x;
    const int b = bid & 7, r = bid >> 3;
    const int strip = r >> 2, jq = r & 3;
    const int i0blk = strip * 64;
    const int jlo = jq * 256, jhi = jlo + 256;
    const int lr = lane & 15, lg4 = lane >> 4;
    const int bh = b * 4 + h;

    bf16x8 qF[4][8];
#pragma unroll
    for (int set = 0; set < 4; ++set) {
        const short* qrow = &Qb[((size_t)bh * 1024 + i0blk + set * 16 + lr) * 256];
#pragma unroll
        for (int kk = 0; kk < 8; ++kk)
            qF[set][kk] = *(const bf16x8*)&qrow[kk * 32 + lg4 * 8];
    }
#pragma unroll
    for (int set = 0; set < 4; ++set)
#pragma unroll
        for (int kk = 0; kk < 8; ++kk) asm volatile("" : "+v"(qF[set][kk]));

    float ec[4];
#pragma unroll
    for (int set = 0; set < 4; ++set)
        ec[set] = ecT[bh * 1024 + i0blk + set * 16 + lr];

    const int iC = t >> 2, jC = (t & 3) * 4;       // combine map: 1 float4/thread
    float* orow = &out[((size_t)((b << 10) + i0blk + iC)) * 1024];
    const float4 m4 = {-1.0e9f, -1.0e9f, -1.0e9f, -1.0e9f};

    int c = 0;
    for (int js = jlo; js < jhi; js += 16) {
        if (js + 15 <= i0blk) {                    // block-uniform dead subtile
            *(float4*)&orow[js + jC] = m4;
            continue;
        }
        bf16x8 kF[8];
        const short* krow = &Kb[((size_t)bh * 1024 + js + lr) * 256];
#pragma unroll
        for (int kk = 0; kk < 8; ++kk)
            kF[kk] = *(const bf16x8*)&krow[kk * 32 + lg4 * 8];
        f32x4 s[4] = {};
#pragma unroll
        for (int kk = 0; kk < 8; ++kk)
#pragma unroll
            for (int set = 0; set < 4; ++set)
                s[set] = __builtin_amdgcn_mfma_f32_16x16x32_bf16(
                    kF[kk], qF[set][kk], s[set], 0, 0, 0);
#pragma unroll
        for (int set = 0; set < 4; ++set)
#pragma unroll
            for (int rr = 0; rr < 4; ++rr)
                Pb[c][h][set * 16 + lr][lg4 * 4 + rr] = __expf(s[set][rr]) * ec[set];
        asm volatile("s_waitcnt lgkmcnt(0)" ::: "memory");
        __builtin_amdgcn_sched_barrier(0);
        __builtin_amdgcn_s_barrier();
        // combine: thread -> (i = i0blk+iC, j = js+jC+e)
        int4 v4 = *(const int4*)&vm[(b << 10) + js + jC];
        const int iG = i0blk + iC;
        float p0 = Pb[c][0][iC][jC + 0] + Pb[c][1][iC][jC + 0]
                 + Pb[c][2][iC][jC + 0] + Pb[c][3][iC][jC + 0];
        float p1 = Pb[c][0][iC][jC + 1] + Pb[c][1][iC][jC + 1]
                 + Pb[c][2][iC][jC + 1] + Pb[c][3][iC][jC + 1];
        float p2 = Pb[c][0][iC][jC + 2] + Pb[c][1][iC][jC + 2]
                 + Pb[c][2][iC][jC + 2] + Pb[c][3][iC][jC + 2];
        float p3 = Pb[c][0][iC][jC + 3] + Pb[c][1][iC][jC + 3]
                 + Pb[c][2][iC][jC + 3] + Pb[c][3][iC][jC + 3];
        float4 o;
        o.x = (v4.x && (js + jC + 0 > iG)) ? __logf(p0) : -1.0e9f;
        o.y = (v4.y && (js + jC + 1 > iG)) ? __logf(p1) : -1.0e9f;
        o.z = (v4.z && (js + jC + 2 > iG)) ? __logf(p2) : -1.0e9f;
        o.w = (v4.w && (js + jC + 3 > iG)) ? __logf(p3) : -1.0e9f;
        *(float4*)&orow[js + jC] = o;
        c ^= 1;                                    // dbuf: next writes other plane
    }
}

// ---------------------------------------------------------------------------
extern "C" void kernel_launch(void* const* d_in, const int* in_sizes, int n_in,
                              void* d_out, int out_size, void* d_ws, size_t ws_size,
                              hipStream_t stream) {
    const float* features = (const float*)d_in[0];
    const int*   vmask    = (const int*)d_in[1];
    const float* Wq       = (const float*)d_in[2];
    const float* bq       = (const float*)d_in[3];
    const float* Wk       = (const float*)d_in[4];
    const float* bk       = (const float*)d_in[5];
    const float* Wg       = (const float*)d_in[6];
    const float* bg       = (const float*)d_in[7];
    float* out = (float*)d_out;

    short* Xb = (short*)d_ws;                  // [8192][1024] bf16
    short* Wt = Xb + 8388608;                  // [2048][1024] bf16 (W^T, q then k)
    short* Qb = Wt + 2097152;                  // [32 bh][1024 i][256 d] bf16 (scaled 1/16)
    short* Kb = Qb + 8388608;                  // [32 bh][1024 j][256 d] bf16
    float* lgA = (float*)(Kb + 8388608);       // [8192][4]
    float* Zp  = lgA + 32768;                  // [4 jq][32 bh][1024 i]
    float* ecT = Zp + 131072;                  // [32 bh][1024 i]

    k_prep<<<2048, 256, 0, stream>>>(features, Wg, bg, Xb, lgA);
    k_cvt_w<<<dim3(64, 32), dim3(32, 8), 0, stream>>>(Wq, Wk, Wt);
    k_gemm<<<256, 512, 0, stream>>>(Xb, Wt, bq, bk, Qb, Kb);
    k_z<<<512, 256, 0, stream>>>(Qb, Kb, vmask, Zp);
    k_c<<<128, 256, 0, stream>>>(lgA, Zp, ecT);
    k_out2<<<512, 256, 0, stream>>>(Qb, Kb, vmask, ecT, out);
}

// Round 7
// 116.253 us; speedup vs baseline: 1.1920x; 1.1920x over previous
//
#include <hip/hip_runtime.h>

// ---------------------------------------------------------------------------
// DagLinkExtractor: B=8, N=1024, HID=1024, NH=4, HD=256
// out[b,i,j] = log Σ_h P[b,h,i,j]·ec[b,h,i]   (alive), else -1e9
//   P = exp(s), s = (Q_h . K_h)/16  (1/16 folded into stored Q)
//   ec[b,h,i] = exp(log_gate) / Z,  Z = Σ_{valid j>i} exp(s)
// k_zp: ONE score pass, LDS-free, barrier-free; Q pinned via inline-asm loads
// (not rematerializable), K reg-double-buffered with counted vmcnt(4).
// ---------------------------------------------------------------------------

typedef __attribute__((ext_vector_type(8))) short bf16x8;
typedef __attribute__((ext_vector_type(4))) short bf16x4;
typedef __attribute__((ext_vector_type(4))) float f32x4;

#define LB __launch_bounds__(256)

__device__ __forceinline__ short f2bf(float f) {
    unsigned u = __float_as_uint(f);
    u += 0x7fffu + ((u >> 16) & 1u);   // RNE
    return (short)(u >> 16);
}
__device__ __forceinline__ float bf2f(short s) {
    return __uint_as_float(((unsigned)(unsigned short)s) << 16);
}

__device__ __forceinline__ void gld16(const void* g, void* l) {
    __builtin_amdgcn_global_load_lds(
        (const __attribute__((address_space(1))) unsigned int*)g,
        (__attribute__((address_space(3))) unsigned int*)l, 16, 0, 0);
}

// opaque 16B load: compiler cannot rematerialize an asm
__device__ __forceinline__ bf16x8 gload(const short* p) {
    bf16x8 r;
    asm volatile("global_load_dwordx4 %0, %1, off" : "=v"(r) : "v"(p) : "memory");
    return r;
}

// ---- 1. fused: Xb = bf16(features), lgA = log_softmax(features@Wg+bg) -------
__global__ LB void k_prep(const float* __restrict__ feat, const float* __restrict__ Wg,
                          const float* __restrict__ bg, short* __restrict__ Xb,
                          float* __restrict__ lgA) {
    int row = blockIdx.x * 4 + (threadIdx.x >> 6);
    int lane = threadIdx.x & 63;
    const float* f = feat + (size_t)row * 1024;
    float g0 = 0.f, g1 = 0.f, g2 = 0.f, g3 = 0.f;
#pragma unroll
    for (int tt = 0; tt < 4; ++tt) {
        int k = tt * 256 + lane * 4;
        float4 x = *(const float4*)&f[k];
        float4 w0 = *(const float4*)&Wg[(k + 0) * 4];
        float4 w1 = *(const float4*)&Wg[(k + 1) * 4];
        float4 w2 = *(const float4*)&Wg[(k + 2) * 4];
        float4 w3 = *(const float4*)&Wg[(k + 3) * 4];
        g0 += x.x * w0.x + x.y * w1.x + x.z * w2.x + x.w * w3.x;
        g1 += x.x * w0.y + x.y * w1.y + x.z * w2.y + x.w * w3.y;
        g2 += x.x * w0.z + x.y * w1.z + x.z * w2.z + x.w * w3.z;
        g3 += x.x * w0.w + x.y * w1.w + x.z * w2.w + x.w * w3.w;
        bf16x4 xv;
        xv[0] = f2bf(x.x); xv[1] = f2bf(x.y); xv[2] = f2bf(x.z); xv[3] = f2bf(x.w);
        *(bf16x4*)&Xb[(size_t)row * 1024 + k] = xv;
    }
#pragma unroll
    for (int off = 32; off; off >>= 1) {
        g0 += __shfl_xor(g0, off); g1 += __shfl_xor(g1, off);
        g2 += __shfl_xor(g2, off); g3 += __shfl_xor(g3, off);
    }
    g0 += bg[0]; g1 += bg[1]; g2 += bg[2]; g3 += bg[3];
    float m = fmaxf(fmaxf(g0, g1), fmaxf(g2, g3));
    float s = __expf(g0 - m) + __expf(g1 - m) + __expf(g2 - m) + __expf(g3 - m);
    float ls = m + __logf(s);
    if (lane == 0) {
        float4 o = {g0 - ls, g1 - ls, g2 - ls, g3 - ls};
        *(float4*)&lgA[row * 4] = o;
    }
}

// ---- 2. Wt[n][k] = W[k][n] (bf16), n<1024 -> Wq, else Wk --------------------
__global__ LB void k_cvt_w(const float* __restrict__ Wq, const float* __restrict__ Wk,
                           short* __restrict__ Wt) {
    __shared__ float tile[32][33];
    int n0 = blockIdx.x * 32, k0 = blockIdx.y * 32;
    const float* W = (n0 < 1024) ? Wq : Wk;
    int nb = n0 & 1023;
    int tx = threadIdx.x, ty = threadIdx.y;
#pragma unroll
    for (int jj = 0; jj < 4; ++jj) {
        int k = ty + jj * 8;
        tile[k][tx] = W[(size_t)(k0 + k) * 1024 + nb + tx];
    }
    __syncthreads();
#pragma unroll
    for (int jj = 0; jj < 4; ++jj) {
        int n = ty + jj * 8;
        Wt[(size_t)(n0 + n) * 1024 + k0 + tx] = f2bf(tile[tx][n]);
    }
}

// ---- 3. GEMM 256x256 tile, BK=64, 4-quadrant-phase, counted vmcnt -----------
__global__ __launch_bounds__(512, 2) void k_gemm(const short* __restrict__ Xb,
                                                 const short* __restrict__ Wt,
                                                 const float* __restrict__ bq,
                                                 const float* __restrict__ bk,
                                                 short* __restrict__ Qb,
                                                 short* __restrict__ Kb) {
    __shared__ short As[2][16384];                 // 2 x 32 KB: [256][64] bf16
    __shared__ short Bs[2][16384];
    const int t = threadIdx.x;
    const int lane = t & 63, wid = t >> 6;
    const int wr = wid >> 2, wc = wid & 3;         // 2 x 4 waves
    const int lr = lane & 15, lg4 = lane >> 4;
    const int wgid = (blockIdx.x & 7) * 32 + (blockIdx.x >> 3);
    const int mt = wgid >> 3, nt = wgid & 7;
    const int m0t = mt * 256, n0t = nt * 256;

    f32x4 acc[8][4] = {};

#define STAGE_A(q, k1, dst)                                                     \
    { int s_ = (q) * 512 + t; int tr_ = s_ >> 3, sl_ = s_ & 7;                  \
      gld16(&Xb[(size_t)(m0t + tr_) * 1024 + (k1) + ((sl_ ^ (tr_ & 7)) * 8)],   \
            &(dst)[s_ * 8]); }
#define STAGE_B(q, k1, dst)                                                     \
    { int s_ = (q) * 512 + t; int tr_ = s_ >> 3, sl_ = s_ & 7;                  \
      gld16(&Wt[(size_t)(n0t + tr_) * 1024 + (k1) + ((sl_ ^ (tr_ & 7)) * 8)],   \
            &(dst)[s_ * 8]); }

    {
        short* Ad = As[0]; short* Bd = Bs[0];
        STAGE_A(0, 0, Ad); STAGE_A(1, 0, Ad); STAGE_A(2, 0, Ad); STAGE_A(3, 0, Ad);
        STAGE_B(0, 0, Bd); STAGE_B(1, 0, Bd); STAGE_B(2, 0, Bd); STAGE_B(3, 0, Bd);
    }
    asm volatile("s_waitcnt vmcnt(0)" ::: "memory");
    __builtin_amdgcn_sched_barrier(0);
    __builtin_amdgcn_s_barrier();

    for (int kt = 0; kt < 16; ++kt) {
        const int cur = kt & 1;
        const short* Ac = As[cur];
        const short* Bc = Bs[cur];
        short* Ad = As[cur ^ 1];
        short* Bd = Bs[cur ^ 1];
        const int k1 = (kt + 1) * 64;
#pragma unroll
        for (int p = 0; p < 4; ++p) {
            const int mh = p >> 1, nh = p & 1;
            bf16x8 aF[4][2], bF[2][2];
#pragma unroll
            for (int m = 0; m < 4; ++m)
#pragma unroll
                for (int ks = 0; ks < 2; ++ks) {
                    int row = wr * 128 + mh * 64 + m * 16 + lr;
                    aF[m][ks] = *(const bf16x8*)
                        &Ac[row * 64 + (((ks * 4 + lg4) ^ (lr & 7)) * 8)];
                }
#pragma unroll
            for (int n = 0; n < 2; ++n)
#pragma unroll
                for (int ks = 0; ks < 2; ++ks) {
                    int row = wc * 64 + (nh * 2 + n) * 16 + lr;
                    bF[n][ks] = *(const bf16x8*)
                        &Bc[row * 64 + (((ks * 4 + lg4) ^ (lr & 7)) * 8)];
                }
            if (kt < 15) {
                if (p == 0)      { STAGE_A(0, k1, Ad); STAGE_A(2, k1, Ad); }
                else if (p == 1) { STAGE_B(0, k1, Bd); STAGE_B(1, k1, Bd); }
                else if (p == 2) { STAGE_B(2, k1, Bd); STAGE_B(3, k1, Bd); }
                else             { STAGE_A(1, k1, Ad); STAGE_A(3, k1, Ad); }
            }
            if (p == 1) {
                if (kt < 15) asm volatile("s_waitcnt vmcnt(4)" ::: "memory");
                else         asm volatile("s_waitcnt vmcnt(0)" ::: "memory");
            } else if (p == 3 && kt < 15) {
                asm volatile("s_waitcnt vmcnt(2)" ::: "memory");
            }
            __builtin_amdgcn_sched_barrier(0);
            __builtin_amdgcn_s_barrier();
            asm volatile("s_waitcnt lgkmcnt(0)" ::: "memory");
            __builtin_amdgcn_sched_barrier(0);
            __builtin_amdgcn_s_setprio(1);
#pragma unroll
            for (int ks = 0; ks < 2; ++ks)
#pragma unroll
                for (int m = 0; m < 4; ++m)
#pragma unroll
                    for (int n = 0; n < 2; ++n)
                        acc[mh * 4 + m][nh * 2 + n] =
                            __builtin_amdgcn_mfma_f32_16x16x32_bf16(
                                aF[m][ks], bF[n][ks], acc[mh * 4 + m][nh * 2 + n],
                                0, 0, 0);
            __builtin_amdgcn_s_setprio(0);
        }
    }
#undef STAGE_A
#undef STAGE_B

#pragma unroll
    for (int mf = 0; mf < 8; ++mf) {
#pragma unroll
        for (int nf = 0; nf < 4; ++nf) {
            int col = n0t + wc * 64 + nf * 16 + lr;
            float bias = (col < 1024) ? bq[col] : bk[col - 1024];
            float scale = (col < 1024) ? 0.0625f : 1.0f;
            short* dst = (col < 1024) ? Qb : Kb;
            int h = (col >> 8) & 3, d = col & 255;
#pragma unroll
            for (int r = 0; r < 4; ++r) {
                int rowg = m0t + wr * 128 + mf * 16 + lg4 * 4 + r;
                int b_ = rowg >> 10, i_ = rowg & 1023;
                float v = (acc[mf][nf][r] + bias) * scale;
                dst[((size_t)(b_ * 4 + h) * 1024 + i_) * 256 + d] = f2bf(v);
            }
        }
    }
}

// ---- 4. k_zp: single score pass. P = bf16(exp(s)) -> Pe[bh][i][j]; Z partials.
// grid 2048 x 64 thr (1 wave/block) = (bh, 64-i strip, j-quarter), bh%8 -> XCD.
// Q: 32 asm loads (pinned, 128 VGPR). K: reg dbuf, prefetch + vmcnt(4).
__global__ __launch_bounds__(64, 2) void k_zp(const short* __restrict__ Qb,
                                              const short* __restrict__ Kb,
                                              const int* __restrict__ vm,
                                              short* __restrict__ Pe,
                                              float* __restrict__ Zp) {
    const int lane = threadIdx.x;
    const int xcd = blockIdx.x & 7, rest = blockIdx.x >> 3;
    const int bh = ((rest >> 6) << 3) | xcd;       // bh % 8 == xcd (K slice / L2)
    const int strip = (rest >> 2) & 15, jq = rest & 3;
    const int b = bh >> 2;
    const int i0 = strip * 64;
    const int jlo = jq * 256, jhi = jlo + 256;
    const int lr = lane & 15, lg4 = lane >> 4;
    const int jstart = (jlo > i0) ? jlo : i0;

    if (jstart >= jhi) {                           // quarter fully below diagonal
        Zp[jq * 32768 + bh * 1024 + i0 + lane] = 0.f;
        return;
    }

    // Q fragments: 4 sets x 8 chunks, inline-asm loads (no remat possible)
    bf16x8 qF[4][8];
#pragma unroll
    for (int set = 0; set < 4; ++set) {
        const short* qr = Qb + ((size_t)bh << 18)
                          + (size_t)(i0 + set * 16 + lr) * 256 + lg4 * 8;
#pragma unroll
        for (int kk = 0; kk < 8; ++kk) qF[set][kk] = gload(qr + kk * 32);
    }

    const short* kb = Kb + ((size_t)bh << 18);
    short* Pp = Pe + ((size_t)bh << 20);
    bf16x8 kA[8], kB[8];
    {
        const short* kr = kb + (size_t)(jstart + lr) * 256 + lg4 * 8;
#pragma unroll
        for (int kk = 0; kk < 8; ++kk) kA[kk] = gload(kr + kk * 32);
    }
    asm volatile("s_waitcnt vmcnt(0)" ::: "memory");
    __builtin_amdgcn_sched_barrier(0);

    const int nst = (jhi - jstart) >> 4;
    float Zl[4] = {0.f, 0.f, 0.f, 0.f};
    int js = jstart;

#define ZP_STEP(KCUR, KNXT, HASNEXT)                                            \
    {                                                                           \
        if (HASNEXT) {                                                          \
            const short* kr_ = kb + (size_t)(js + 16 + lr) * 256 + lg4 * 8;     \
            KNXT[0] = gload(kr_);        KNXT[1] = gload(kr_ + 32);             \
            KNXT[2] = gload(kr_ + 64);   KNXT[3] = gload(kr_ + 96);             \
            KNXT[4] = gload(kr_ + 128);  KNXT[5] = gload(kr_ + 160);            \
            KNXT[6] = gload(kr_ + 192);  KNXT[7] = gload(kr_ + 224);            \
        }                                                                       \
        f32x4 s0 = {}, s1 = {}, s2 = {}, s3 = {};                               \
        _Pragma("unroll")                                                       \
        for (int kk = 0; kk < 8; ++kk) {                                        \
            s0 = __builtin_amdgcn_mfma_f32_16x16x32_bf16(KCUR[kk], qF[0][kk], s0, 0, 0, 0); \
            s1 = __builtin_amdgcn_mfma_f32_16x16x32_bf16(KCUR[kk], qF[1][kk], s1, 0, 0, 0); \
            s2 = __builtin_amdgcn_mfma_f32_16x16x32_bf16(KCUR[kk], qF[2][kk], s2, 0, 0, 0); \
            s3 = __builtin_amdgcn_mfma_f32_16x16x32_bf16(KCUR[kk], qF[3][kk], s3, 0, 0, 0); \
        }                                                                       \
        const int jb = js + lg4 * 4;                                            \
        int4 v4 = *(const int4*)&vm[(b << 10) + jb];                            \
        _Pragma("unroll")                                                       \
        for (int set = 0; set < 4; ++set) {                                     \
            f32x4 sv = (set == 0) ? s0 : (set == 1) ? s1 : (set == 2) ? s2 : s3;\
            const int iL = i0 + set * 16 + lr;                                  \
            float e0 = __expf(sv[0]), e1 = __expf(sv[1]);                       \
            float e2 = __expf(sv[2]), e3 = __expf(sv[3]);                       \
            Zl[set] += (v4.x && (jb + 0 > iL)) ? e0 : 0.f;                      \
            Zl[set] += (v4.y && (jb + 1 > iL)) ? e1 : 0.f;                      \
            Zl[set] += (v4.z && (jb + 2 > iL)) ? e2 : 0.f;                      \
            Zl[set] += (v4.w && (jb + 3 > iL)) ? e3 : 0.f;                      \
            bf16x4 pv;                                                          \
            pv[0] = f2bf(e0); pv[1] = f2bf(e1);                                 \
            pv[2] = f2bf(e2); pv[3] = f2bf(e3);                                 \
            *(bf16x4*)&Pp[(size_t)iL * 1024 + jb] = pv;                         \
        }                                                                       \
        if (HASNEXT) {                                                          \
            asm volatile("s_waitcnt vmcnt(4)" ::: "memory");                    \
            __builtin_amdgcn_sched_barrier(0);                                  \
        }                                                                       \
        js += 16;                                                               \
    }

    int stp = 0;
    for (; stp + 2 <= nst; stp += 2) {
        ZP_STEP(kA, kB, true)
        ZP_STEP(kB, kA, (stp + 2 < nst))
    }
    if (stp < nst) ZP_STEP(kA, kB, false)
#undef ZP_STEP

    // reduce Z over the 4 lg4 groups (j sub-lanes); lanes 0-15 hold column sums
#pragma unroll
    for (int set = 0; set < 4; ++set) {
        Zl[set] += __shfl_xor(Zl[set], 16);
        Zl[set] += __shfl_xor(Zl[set], 32);
    }
    if (lane < 16) {
#pragma unroll
        for (int set = 0; set < 4; ++set)
            Zp[jq * 32768 + bh * 1024 + i0 + set * 16 + lane] = Zl[set];
    }
}

// ---- 5. ecF[(b,i)][h] = exp(lg)/Z  (Z==0 -> 0: dead row) --------------------
__global__ LB void k_c(const float* __restrict__ lgA, const float* __restrict__ Zp,
                       float* __restrict__ ecF) {
    int idx = blockIdx.x * 256 + threadIdx.x;      // 8192 = b*1024+i
    int b = idx >> 10, i = idx & 1023;
    float4 lg = *(const float4*)&lgA[idx * 4];
    float4 o;
#pragma unroll
    for (int h = 0; h < 4; ++h) {
        int base = (b * 4 + h) * 1024 + i;
        float Zv = Zp[base] + Zp[32768 + base] + Zp[65536 + base] + Zp[98304 + base];
        float lgv = (h == 0) ? lg.x : (h == 1) ? lg.y : (h == 2) ? lg.z : lg.w;
        float e = (Zv > 0.f) ? __expf(lgv) / Zv : 0.f;
        if (h == 0) o.x = e; else if (h == 1) o.y = e;
        else if (h == 2) o.z = e; else o.w = e;
    }
    *(float4*)&ecF[idx * 4] = o;
}

// ---- 6. streaming epilogue: out = alive ? log(dot(P, ec)) : -1e9 ------------
// grid 8192 = (b,i); 256 thr x 1 float4 each
__global__ LB void k_final(const short* __restrict__ Pe, const int* __restrict__ vm,
                           const float* __restrict__ ecF, float* __restrict__ out) {
    const int blk = blockIdx.x;                    // b*1024 + i
    const int b = blk >> 10, i = blk & 1023;
    const int j0 = threadIdx.x * 4;
    float4 o = {-1.0e9f, -1.0e9f, -1.0e9f, -1.0e9f};
    if (j0 + 3 > i) {
        float4 ec = *(const float4*)&ecF[blk * 4];
        int4 v4 = *(const int4*)&vm[(b << 10) + j0];
        const size_t off = ((size_t)(i) << 10) + j0;
        bf16x4 p0 = *(const bf16x4*)&Pe[(((size_t)(b * 4 + 0)) << 20) + off];
        bf16x4 p1 = *(const bf16x4*)&Pe[(((size_t)(b * 4 + 1)) << 20) + off];
        bf16x4 p2 = *(const bf16x4*)&Pe[(((size_t)(b * 4 + 2)) << 20) + off];
        bf16x4 p3 = *(const bf16x4*)&Pe[(((size_t)(b * 4 + 3)) << 20) + off];
        float a0 = bf2f(p0[0]) * ec.x + bf2f(p1[0]) * ec.y
                 + bf2f(p2[0]) * ec.z + bf2f(p3[0]) * ec.w;
        float a1 = bf2f(p0[1]) * ec.x + bf2f(p1[1]) * ec.y
                 + bf2f(p2[1]) * ec.z + bf2f(p3[1]) * ec.w;
        float a2 = bf2f(p0[2]) * ec.x + bf2f(p1[2]) * ec.y
                 + bf2f(p2[2]) * ec.z + bf2f(p3[2]) * ec.w;
        float a3 = bf2f(p0[3]) * ec.x + bf2f(p1[3]) * ec.y
                 + bf2f(p2[3]) * ec.z + bf2f(p3[3]) * ec.w;
        o.x = (v4.x && (j0 + 0 > i)) ? __logf(a0) : -1.0e9f;
        o.y = (v4.y && (j0 + 1 > i)) ? __logf(a1) : -1.0e9f;
        o.z = (v4.z && (j0 + 2 > i)) ? __logf(a2) : -1.0e9f;
        o.w = (v4.w && (j0 + 3 > i)) ? __logf(a3) : -1.0e9f;
    }
    *(float4*)&out[((size_t)blk << 10) + j0] = o;
}

// ---------------------------------------------------------------------------
extern "C" void kernel_launch(void* const* d_in, const int* in_sizes, int n_in,
                              void* d_out, int out_size, void* d_ws, size_t ws_size,
                              hipStream_t stream) {
    const float* features = (const float*)d_in[0];
    const int*   vmask    = (const int*)d_in[1];
    const float* Wq       = (const float*)d_in[2];
    const float* bq       = (const float*)d_in[3];
    const float* Wk       = (const float*)d_in[4];
    const float* bk       = (const float*)d_in[5];
    const float* Wg       = (const float*)d_in[6];
    const float* bg       = (const float*)d_in[7];
    float* out = (float*)d_out;

    // ws carve (~101.5 MB peak, same as r5 which fit). Pe overlaps Xb+Wt.
    short* Pe = (short*)d_ws;                  // [32 bh][1024 i][1024 j] bf16 = 67 MB
    short* Xb = (short*)d_ws;                  // [8192][1024] bf16 (dead after k_gemm)
    short* Wt = Xb + 8388608;                  // [2048][1024] bf16 (dead after k_gemm)
    short* Qb = Pe + 33554432;                 // [32 bh][1024 i][256 d] bf16 (scaled 1/16)
    short* Kb = Qb + 8388608;                  // [32 bh][1024 j][256 d] bf16
    float* lgA = (float*)(Kb + 8388608);       // [8192][4]
    float* Zp  = lgA + 32768;                  // [4 jq][32 bh][1024 i]
    float* ecF = Zp + 131072;                  // [8192][4]

    k_prep<<<2048, 256, 0, stream>>>(features, Wg, bg, Xb, lgA);
    k_cvt_w<<<dim3(64, 32), dim3(32, 8), 0, stream>>>(Wq, Wk, Wt);
    k_gemm<<<256, 512, 0, stream>>>(Xb, Wt, bq, bk, Qb, Kb);
    k_zp<<<2048, 64, 0, stream>>>(Qb, Kb, vmask, Pe, Zp);
    k_c<<<32, 256, 0, stream>>>(lgA, Zp, ecF);
    k_final<<<8192, 256, 0, stream>>>(Pe, vmask, ecF, out);
}